// Round 5
// baseline (165.891 us; speedup 1.0000x reference)
//
#include <hip/hip_runtime.h>
#include <hip/hip_cooperative_groups.h>
#include <math.h>

namespace cg = cooperative_groups;

#define NN 18
#define T_STEPS 1280
#define T1LEN 1278   // T-2 (after conv1)
#define T2LEN 1276   // T-4 (after conv2)
#define NPOS1 (T1LEN * NN)   // 23004
#define XTOT  (T_STEPS * NN) // 23040
#define PC1 32
#define NCHUNK1 ((NPOS1 + PC1 - 1) / PC1)  // 719
#define TC2 64
#define NCHUNK2 ((T2LEN + TC2 - 1) / TC2)  // 20
#define NBLK (NCHUNK2 * NN)                // 360

typedef __attribute__((ext_vector_type(8))) short short8;
typedef __attribute__((ext_vector_type(4))) float f32x4;

__device__ __forceinline__ unsigned short f2bf(float v) {
    unsigned u = __builtin_bit_cast(unsigned, v);
    u = u + 0x7fff + ((u >> 16) & 1);          // RNE
    return (unsigned short)(u >> 16);
}
__device__ __forceinline__ float bf2f(unsigned short h) {
    unsigned u = ((unsigned)h) << 16;
    return __builtin_bit_cast(float, u);
}

struct Params {
    const float *x, *w1a, *b1a, *w1b, *b1b, *w1c, *b1c, *cw, *cb;
    const float *w2a, *w2b, *w2c, *b2a, *b2b, *b2c, *gamma, *beta, *fcw, *fcb;
    unsigned short *WBhi, *WBlo, *T1hi, *T1lo;
    float *parts, *dpart, *out;
};

// =================== single cooperative mega-kernel ===================
__global__ __launch_bounds__(256, 2) void k_mega(Params p) {
    __shared__ __align__(16) char smem[19456];
    cg::grid_group grid = cg::this_grid();
    int tid = threadIdx.x;
    int b = blockIdx.x;

    // ---- Phase A: conv2 weight hi/lo split, layout [kb][col][klocal] ----
    {
        int i = b * 256 + tid;
        if (i < 6 * 192 * 32) {
            int klocal = i & 31;
            int col = (i >> 5) % 192;
            int kb = i / (192 * 32);
            int conv = col >> 6, co = col & 63;
            int k = kb >> 1, ci = (kb & 1) * 32 + klocal;
            const float* w = (conv == 0) ? p.w2a : (conv == 1 ? p.w2b : p.w2c);
            float v = w[co * 192 + ci * 3 + k];
            unsigned short hi = f2bf(v);
            p.WBhi[i] = hi;
            p.WBlo[i] = f2bf(v - bf2f(hi));
        }
    }

    // ---- Phase B: normalize + conv1(GLU) + cheb + relu -> T1 hi/lo ----
    {
        float* xs = (float*)smem;                       // 68 floats
        float (*tile)[65] = (float (*)[65])(smem + 512);// 32x65 floats
        int c = tid & 63, w = tid >> 6;
        float wa0 = p.w1a[c*3], wa1 = p.w1a[c*3+1], wa2 = p.w1a[c*3+2];
        float wb0 = p.w1b[c*3], wb1 = p.w1b[c*3+1], wb2 = p.w1b[c*3+2];
        float wc0 = p.w1c[c*3], wc1 = p.w1c[c*3+1], wc2 = p.w1c[c*3+2];
        float ba = p.b1a[c], bb = p.b1b[c], bc = p.b1c[c];
        float cbias = p.cb[c];
        for (int ch = b; ch < NCHUNK1; ch += NBLK) {
            int p0 = ch * PC1;
            int np = min(PC1, NPOS1 - p0);
            __syncthreads();
            for (int idx = tid; idx < PC1 + 36; idx += 256) {
                int g = p0 + idx;
                float v = (g < XTOT) ? p.x[g] : 0.f;
                xs[idx] = v / fmaxf(fabsf(v), 1e-12f);
            }
            __syncthreads();
            #pragma unroll
            for (int j = 0; j < 8; ++j) {
                int pl = w * 8 + j;
                float x0 = xs[pl], x1 = xs[pl + 18], x2 = xs[pl + 36];
                float pa = fmaf(wa2, x2, fmaf(wa1, x1, fmaf(wa0, x0, ba)));
                float pb = fmaf(wb2, x2, fmaf(wb1, x1, fmaf(wb0, x0, bb)));
                float pc_ = fmaf(wc2, x2, fmaf(wc1, x1, fmaf(wc0, x0, bc)));
                float q = 1.0f / (1.0f + expf(-pb));
                tile[pl][c] = fmaxf(pa * q + pc_, 0.f);
            }
            __syncthreads();
            float acc[8];
            #pragma unroll
            for (int j = 0; j < 8; ++j) acc[j] = cbias;
            float wcur = p.cw[c];
            for (int cc = 0; cc < 64; ++cc) {
                float wnxt = p.cw[((cc + 1) & 63) * 64 + c];
                #pragma unroll
                for (int j = 0; j < 8; ++j)
                    acc[j] = fmaf(tile[w * 8 + j][cc], wcur, acc[j]);
                wcur = wnxt;
            }
            #pragma unroll
            for (int j = 0; j < 8; ++j) {
                int pp = w * 8 + j;
                if (pp < np) {
                    float v = fmaxf(acc[j], 0.0f);
                    unsigned short hi = f2bf(v);
                    int idx = (p0 + pp) * 64 + c;
                    p.T1hi[idx] = hi;
                    p.T1lo[idx] = f2bf(v - bf2f(hi));
                }
            }
        }
    }

    grid.sync();

    // ---- Phase C: conv2 split-bf16 MFMA + GLU; h stays in registers ----
    float h[16];
    int node = b / NCHUNK2;
    int chunk = b % NCHUNK2;
    int t0 = chunk * TC2;
    int l = tid & 63, w = tid >> 6;
    int co = w * 16 + (l & 15);
    {
        uint4* ldsH = (uint4*)smem;             // 528
        uint4* ldsL = (uint4*)(smem + 8448);    // 528
        float* rs = (float*)(smem + 16896);
        float* rq = (float*)(smem + 17920);
        int rows_valid = min(66, T1LEN - t0);
        const uint4* gh = (const uint4*)p.T1hi;
        const uint4* gl = (const uint4*)p.T1lo;
        for (int idx = tid; idx < 528; idx += 256) {
            int row = idx >> 3, cb2 = idx & 7;
            uint4 vh = {0,0,0,0}, vl = {0,0,0,0};
            if (row < rows_valid) {
                int g = ((t0 + row) * NN + node) * 8 + cb2;
                vh = gh[g]; vl = gl[g];
            }
            int s = row * 8 + (cb2 ^ (row & 7));
            ldsH[s] = vh; ldsL[s] = vl;
        }
        __syncthreads();
        const uint4* wbh = (const uint4*)p.WBhi;
        const uint4* wbl = (const uint4*)p.WBlo;
        f32x4 acc[4][3];
        #pragma unroll
        for (int mt = 0; mt < 4; ++mt)
            #pragma unroll
            for (int ct = 0; ct < 3; ++ct)
                acc[mt][ct] = (f32x4){0.f, 0.f, 0.f, 0.f};
        for (int kb = 0; kb < 6; ++kb) {
            short8 bh[3], bl[3];
            #pragma unroll
            for (int ct = 0; ct < 3; ++ct) {
                int col = (w + 4 * ct) * 16 + (l & 15);
                int gi = (kb * 192 + col) * 4 + (l >> 4);
                bh[ct] = __builtin_bit_cast(short8, wbh[gi]);
                bl[ct] = __builtin_bit_cast(short8, wbl[gi]);
            }
            #pragma unroll
            for (int mt = 0; mt < 4; ++mt) {
                int row = mt * 16 + (l & 15) + (kb >> 1);
                int cb2 = (kb & 1) * 4 + (l >> 4);
                int si = row * 8 + (cb2 ^ (row & 7));
                short8 ah = __builtin_bit_cast(short8, ldsH[si]);
                short8 al = __builtin_bit_cast(short8, ldsL[si]);
                acc[mt][0] = __builtin_amdgcn_mfma_f32_16x16x32_bf16(ah, bh[0], acc[mt][0], 0, 0, 0);
                acc[mt][1] = __builtin_amdgcn_mfma_f32_16x16x32_bf16(ah, bh[1], acc[mt][1], 0, 0, 0);
                acc[mt][2] = __builtin_amdgcn_mfma_f32_16x16x32_bf16(ah, bh[2], acc[mt][2], 0, 0, 0);
                acc[mt][0] = __builtin_amdgcn_mfma_f32_16x16x32_bf16(al, bh[0], acc[mt][0], 0, 0, 0);
                acc[mt][1] = __builtin_amdgcn_mfma_f32_16x16x32_bf16(al, bh[1], acc[mt][1], 0, 0, 0);
                acc[mt][2] = __builtin_amdgcn_mfma_f32_16x16x32_bf16(al, bh[2], acc[mt][2], 0, 0, 0);
                acc[mt][0] = __builtin_amdgcn_mfma_f32_16x16x32_bf16(ah, bl[0], acc[mt][0], 0, 0, 0);
                acc[mt][1] = __builtin_amdgcn_mfma_f32_16x16x32_bf16(ah, bl[1], acc[mt][1], 0, 0, 0);
                acc[mt][2] = __builtin_amdgcn_mfma_f32_16x16x32_bf16(ah, bl[2], acc[mt][2], 0, 0, 0);
            }
        }
        float ba = p.b2a[co], bb = p.b2b[co], bc = p.b2c[co];
        float s_sum = 0.f, s_sq = 0.f;
        #pragma unroll
        for (int mt = 0; mt < 4; ++mt) {
            #pragma unroll
            for (int r = 0; r < 4; ++r) {
                int t = t0 + mt * 16 + (l >> 4) * 4 + r;
                float hv = 0.f;
                if (t < T2LEN) {
                    float P = acc[mt][0][r] + ba, Q = acc[mt][1][r] + bb, Cc = acc[mt][2][r] + bc;
                    float qs = 1.f / (1.f + expf(-Q));
                    hv = fmaxf(fmaf(P, qs, Cc), 0.f);
                    s_sum += hv;
                    s_sq = fmaf(hv, hv, s_sq);
                }
                h[mt * 4 + r] = hv;
            }
        }
        rs[tid] = s_sum; rq[tid] = s_sq;
        __syncthreads();
        for (int off = 128; off > 0; off >>= 1) {
            if (tid < off) { rs[tid] += rs[tid + off]; rq[tid] += rq[tid + off]; }
            __syncthreads();
        }
        if (tid == 0) {
            p.parts[b * 2]     = rs[0];
            p.parts[b * 2 + 1] = rq[0];
        }
    }

    grid.sync();

    // ---- Phase D: stats finalize (redundant per block) + BN + relu + dot ----
    {
        float s = 0.f, q = 0.f;
        #pragma unroll
        for (int i = 0; i < NCHUNK2; ++i) {
            s += p.parts[(node * NCHUNK2 + i) * 2];
            q += p.parts[(node * NCHUNK2 + i) * 2 + 1];
        }
        float cnt = (float)(T2LEN * 64);
        float mean = s / cnt;
        float var = q / cnt - mean * mean;
        float istd = rsqrtf(var + 1e-5f);
        float g = p.gamma[node], bt = p.beta[node];
        float acc = 0.f;
        #pragma unroll
        for (int mt = 0; mt < 4; ++mt) {
            #pragma unroll
            for (int r = 0; r < 4; ++r) {
                int t = t0 + mt * 16 + (l >> 4) * 4 + r;
                if (t < T2LEN) {
                    float v = fmaxf((h[mt * 4 + r] - mean) * istd * g + bt, 0.f);
                    acc = fmaf(v, p.fcw[(t * NN + node) * 64 + co], acc);
                }
            }
        }
        float* r = (float*)smem;
        r[tid] = acc;
        __syncthreads();
        for (int off = 128; off > 0; off >>= 1) {
            if (tid < off) r[tid] += r[tid + off];
            __syncthreads();
        }
        if (tid == 0) p.dpart[b] = r[0];
    }

    grid.sync();

    // ---- Phase E: final reduce ----
    if (b == 0) {
        float v = 0.f;
        for (int i = tid; i < NBLK; i += 256) v += p.dpart[i];
        float* r = (float*)smem;
        r[tid] = v;
        __syncthreads();
        for (int off = 128; off > 0; off >>= 1) {
            if (tid < off) r[tid] += r[tid + off];
            __syncthreads();
        }
        if (tid == 0) p.out[0] = r[0] + p.fcb[0];
    }
}

// =================== fallback chain (R3, proven) ===================
__global__ void k_wprep2(const float* __restrict__ wa, const float* __restrict__ wb,
                         const float* __restrict__ wc,
                         unsigned short* __restrict__ WBhi, unsigned short* __restrict__ WBlo) {
    int i = blockIdx.x * 256 + threadIdx.x;
    if (i >= 6 * 192 * 32) return;
    int klocal = i & 31;
    int col = (i >> 5) % 192;
    int kb = i / (192 * 32);
    int conv = col >> 6, co = col & 63;
    int k = kb >> 1, ci = (kb & 1) * 32 + klocal;
    const float* w = (conv == 0) ? wa : (conv == 1 ? wb : wc);
    float v = w[co * 192 + ci * 3 + k];
    unsigned short hi = f2bf(v);
    WBhi[i] = hi;
    WBlo[i] = f2bf(v - bf2f(hi));
}

__global__ __launch_bounds__(256) void k_fused1(const float* __restrict__ x,
        const float* __restrict__ w1a, const float* __restrict__ b1a,
        const float* __restrict__ w1b, const float* __restrict__ b1b,
        const float* __restrict__ w1c, const float* __restrict__ b1c,
        const float* __restrict__ cw, const float* __restrict__ cb,
        unsigned short* __restrict__ T1hi, unsigned short* __restrict__ T1lo) {
    __shared__ float xs[72];
    __shared__ float tile[PC1][65];
    int p0 = blockIdx.x * PC1;
    int np = min(PC1, NPOS1 - p0);
    for (int idx = threadIdx.x; idx < PC1 + 36; idx += 256) {
        int g = p0 + idx;
        float v = (g < XTOT) ? x[g] : 0.f;
        xs[idx] = v / fmaxf(fabsf(v), 1e-12f);
    }
    __syncthreads();
    int c = threadIdx.x & 63;
    int w = threadIdx.x >> 6;
    float wa0 = w1a[c*3], wa1 = w1a[c*3+1], wa2 = w1a[c*3+2];
    float wb0 = w1b[c*3], wb1 = w1b[c*3+1], wb2 = w1b[c*3+2];
    float wc0 = w1c[c*3], wc1 = w1c[c*3+1], wc2 = w1c[c*3+2];
    float ba = b1a[c], bb = b1b[c], bc = b1c[c];
    #pragma unroll
    for (int j = 0; j < 8; ++j) {
        int pl = w * 8 + j;
        float x0 = xs[pl], x1 = xs[pl + 18], x2 = xs[pl + 36];
        float pa = fmaf(wa2, x2, fmaf(wa1, x1, fmaf(wa0, x0, ba)));
        float pb = fmaf(wb2, x2, fmaf(wb1, x1, fmaf(wb0, x0, bb)));
        float pc_ = fmaf(wc2, x2, fmaf(wc1, x1, fmaf(wc0, x0, bc)));
        float q = 1.0f / (1.0f + expf(-pb));
        tile[pl][c] = fmaxf(pa * q + pc_, 0.f);
    }
    __syncthreads();
    float acc[8];
    float bias = cb[c];
    #pragma unroll
    for (int j = 0; j < 8; ++j) acc[j] = bias;
    float wcur = cw[c];
    for (int cc = 0; cc < 64; ++cc) {
        float wnxt = cw[((cc + 1) & 63) * 64 + c];
        #pragma unroll
        for (int j = 0; j < 8; ++j)
            acc[j] = fmaf(tile[w * 8 + j][cc], wcur, acc[j]);
        wcur = wnxt;
    }
    #pragma unroll
    for (int j = 0; j < 8; ++j) {
        int pp = w * 8 + j;
        if (pp < np) {
            float v = fmaxf(acc[j], 0.0f);
            unsigned short hi = f2bf(v);
            int idx = (p0 + pp) * 64 + c;
            T1hi[idx] = hi;
            T1lo[idx] = f2bf(v - bf2f(hi));
        }
    }
}

__global__ __launch_bounds__(256) void k_conv2m(
        const unsigned short* __restrict__ T1hi, const unsigned short* __restrict__ T1lo,
        const unsigned short* __restrict__ WBhi, const unsigned short* __restrict__ WBlo,
        const float* __restrict__ b2a, const float* __restrict__ b2b,
        const float* __restrict__ b2c,
        float* __restrict__ T2, float* __restrict__ partials) {
    __shared__ uint4 ldsH[528], ldsL[528];
    int t0 = blockIdx.x * TC2;
    int n  = blockIdx.y;
    int tid = threadIdx.x;
    int rows_valid = min(66, T1LEN - t0);
    const uint4* gh = (const uint4*)T1hi;
    const uint4* gl = (const uint4*)T1lo;
    for (int idx = tid; idx < 528; idx += 256) {
        int row = idx >> 3, cb = idx & 7;
        uint4 vh = {0,0,0,0}, vl = {0,0,0,0};
        if (row < rows_valid) {
            int g = ((t0 + row) * NN + n) * 8 + cb;
            vh = gh[g]; vl = gl[g];
        }
        int s = row * 8 + (cb ^ (row & 7));
        ldsH[s] = vh; ldsL[s] = vl;
    }
    int l = tid & 63, w = tid >> 6;
    const uint4* wbh = (const uint4*)WBhi;
    const uint4* wbl = (const uint4*)WBlo;
    int co = w * 16 + (l & 15);
    float ba = b2a[co], bb = b2b[co], bc = b2c[co];
    __syncthreads();
    f32x4 acc[4][3];
    #pragma unroll
    for (int mt = 0; mt < 4; ++mt)
        #pragma unroll
        for (int ct = 0; ct < 3; ++ct)
            acc[mt][ct] = (f32x4){0.f, 0.f, 0.f, 0.f};
    for (int kb = 0; kb < 6; ++kb) {
        short8 bh[3], bl[3];
        #pragma unroll
        for (int ct = 0; ct < 3; ++ct) {
            int col = (w + 4 * ct) * 16 + (l & 15);
            int gi = (kb * 192 + col) * 4 + (l >> 4);
            bh[ct] = __builtin_bit_cast(short8, wbh[gi]);
            bl[ct] = __builtin_bit_cast(short8, wbl[gi]);
        }
        #pragma unroll
        for (int mt = 0; mt < 4; ++mt) {
            int row = mt * 16 + (l & 15) + (kb >> 1);
            int cb2 = (kb & 1) * 4 + (l >> 4);
            int si = row * 8 + (cb2 ^ (row & 7));
            short8 ah = __builtin_bit_cast(short8, ldsH[si]);
            short8 al = __builtin_bit_cast(short8, ldsL[si]);
            acc[mt][0] = __builtin_amdgcn_mfma_f32_16x16x32_bf16(ah, bh[0], acc[mt][0], 0, 0, 0);
            acc[mt][1] = __builtin_amdgcn_mfma_f32_16x16x32_bf16(ah, bh[1], acc[mt][1], 0, 0, 0);
            acc[mt][2] = __builtin_amdgcn_mfma_f32_16x16x32_bf16(ah, bh[2], acc[mt][2], 0, 0, 0);
            acc[mt][0] = __builtin_amdgcn_mfma_f32_16x16x32_bf16(al, bh[0], acc[mt][0], 0, 0, 0);
            acc[mt][1] = __builtin_amdgcn_mfma_f32_16x16x32_bf16(al, bh[1], acc[mt][1], 0, 0, 0);
            acc[mt][2] = __builtin_amdgcn_mfma_f32_16x16x32_bf16(al, bh[2], acc[mt][2], 0, 0, 0);
            acc[mt][0] = __builtin_amdgcn_mfma_f32_16x16x32_bf16(ah, bl[0], acc[mt][0], 0, 0, 0);
            acc[mt][1] = __builtin_amdgcn_mfma_f32_16x16x32_bf16(ah, bl[1], acc[mt][1], 0, 0, 0);
            acc[mt][2] = __builtin_amdgcn_mfma_f32_16x16x32_bf16(ah, bl[2], acc[mt][2], 0, 0, 0);
        }
    }
    float s_sum = 0.f, s_sq = 0.f;
    #pragma unroll
    for (int mt = 0; mt < 4; ++mt) {
        #pragma unroll
        for (int r = 0; r < 4; ++r) {
            int t = t0 + mt * 16 + (l >> 4) * 4 + r;
            if (t < T2LEN) {
                float P = acc[mt][0][r] + ba, Q = acc[mt][1][r] + bb, Cc = acc[mt][2][r] + bc;
                float q = 1.f / (1.f + expf(-Q));
                float hv = fmaxf(fmaf(P, q, Cc), 0.f);
                T2[(t * NN + n) * 64 + co] = hv;
                s_sum += hv;
                s_sq = fmaf(hv, hv, s_sq);
            }
        }
    }
    __shared__ float rs[256], rq[256];
    rs[tid] = s_sum; rq[tid] = s_sq;
    __syncthreads();
    for (int off = 128; off > 0; off >>= 1) {
        if (tid < off) { rs[tid] += rs[tid + off]; rq[tid] += rq[tid + off]; }
        __syncthreads();
    }
    if (tid == 0) {
        partials[(n * NCHUNK2 + blockIdx.x) * 2]     = rs[0];
        partials[(n * NCHUNK2 + blockIdx.x) * 2 + 1] = rq[0];
    }
}

__global__ __launch_bounds__(64) void k_statsfin(const float* __restrict__ partials,
                                                 float* __restrict__ stats) {
    int n = blockIdx.x;
    int l = threadIdx.x;
    float s = (l < NCHUNK2) ? partials[(n * NCHUNK2 + l) * 2]     : 0.f;
    float q = (l < NCHUNK2) ? partials[(n * NCHUNK2 + l) * 2 + 1] : 0.f;
    #pragma unroll
    for (int off = 32; off > 0; off >>= 1) {
        s += __shfl_down(s, off);
        q += __shfl_down(q, off);
    }
    if (l == 0) {
        float cnt = (float)(T2LEN * 64);
        float mean = s / cnt;
        float var = q / cnt - mean * mean;
        stats[n * 2]     = mean;
        stats[n * 2 + 1] = rsqrtf(var + 1e-5f);
    }
}

#define DOT_BLOCKS 512
__global__ __launch_bounds__(256) void k_dot(const float* __restrict__ T2,
        const float* __restrict__ stats,
        const float* __restrict__ gamma, const float* __restrict__ beta,
        const float* __restrict__ fcw, float* __restrict__ dpart) {
    float acc = 0.f;
    const int total4 = T2LEN * NN * 64 / 4;
    const float4* T24 = (const float4*)T2;
    const float4* fw4 = (const float4*)fcw;
    for (int i = blockIdx.x * 256 + threadIdx.x; i < total4; i += DOT_BLOCKS * 256) {
        float4 t = T24[i];
        float4 f = fw4[i];
        int n = (i >> 4) % NN;
        float mu = stats[n * 2], is = stats[n * 2 + 1];
        float g = gamma[n], bt = beta[n];
        float v0 = fmaxf((t.x - mu) * is * g + bt, 0.f);
        float v1 = fmaxf((t.y - mu) * is * g + bt, 0.f);
        float v2 = fmaxf((t.z - mu) * is * g + bt, 0.f);
        float v3 = fmaxf((t.w - mu) * is * g + bt, 0.f);
        acc = fmaf(v0, f.x, acc);
        acc = fmaf(v1, f.y, acc);
        acc = fmaf(v2, f.z, acc);
        acc = fmaf(v3, f.w, acc);
    }
    __shared__ float r[256];
    r[threadIdx.x] = acc;
    __syncthreads();
    for (int off = 128; off > 0; off >>= 1) {
        if (threadIdx.x < off) r[threadIdx.x] += r[threadIdx.x + off];
        __syncthreads();
    }
    if (threadIdx.x == 0) dpart[blockIdx.x] = r[0];
}

__global__ __launch_bounds__(512) void k_final(const float* __restrict__ dpart,
                                               const float* __restrict__ fcb,
                                               float* __restrict__ out) {
    __shared__ float r[512];
    r[threadIdx.x] = dpart[threadIdx.x];
    __syncthreads();
    for (int off = 256; off > 0; off >>= 1) {
        if (threadIdx.x < off) r[threadIdx.x] += r[threadIdx.x + off];
        __syncthreads();
    }
    if (threadIdx.x == 0) out[0] = r[0] + fcb[0];
}

extern "C" void kernel_launch(void* const* d_in, const int* in_sizes, int n_in,
                              void* d_out, int out_size, void* d_ws, size_t ws_size,
                              hipStream_t stream) {
    const float* x     = (const float*)d_in[0];
    // d_in[1] edge_index, d_in[2] edge_weight: unused (ChebConv K=1 -> identity only)
    const float* w1a   = (const float*)d_in[3];
    const float* b1a   = (const float*)d_in[4];
    const float* w1b   = (const float*)d_in[5];
    const float* b1b   = (const float*)d_in[6];
    const float* w1c   = (const float*)d_in[7];
    const float* b1c   = (const float*)d_in[8];
    const float* chw   = (const float*)d_in[9];
    const float* chb   = (const float*)d_in[10];
    const float* w2a   = (const float*)d_in[11];
    const float* b2a   = (const float*)d_in[12];
    const float* w2b   = (const float*)d_in[13];
    const float* b2b   = (const float*)d_in[14];
    const float* w2c   = (const float*)d_in[15];
    const float* b2c   = (const float*)d_in[16];
    const float* gamma = (const float*)d_in[17];
    const float* beta  = (const float*)d_in[18];
    const float* fcw   = (const float*)d_in[19];
    const float* fcb   = (const float*)d_in[20];
    float* out = (float*)d_out;

    char* base = (char*)d_ws;
    float*          T2v   = (float*)(base);                    // 5879808 B (fallback only)
    unsigned short* T1hi  = (unsigned short*)(base + 5879808);
    unsigned short* T1lo  = (unsigned short*)(base + 8824320);
    unsigned short* WBhi  = (unsigned short*)(base + 11768832);
    unsigned short* WBlo  = (unsigned short*)(base + 11842560);
    float*          parts = (float*)(base + 11916288);         // 720 f
    float*          stats = (float*)(base + 11920384);         // 36 f (fallback only)
    float*          dpart = (float*)(base + 11921408);         // 512 f

    Params prm;
    prm.x = x; prm.w1a = w1a; prm.b1a = b1a; prm.w1b = w1b; prm.b1b = b1b;
    prm.w1c = w1c; prm.b1c = b1c; prm.cw = chw; prm.cb = chb;
    prm.w2a = w2a; prm.w2b = w2b; prm.w2c = w2c;
    prm.b2a = b2a; prm.b2b = b2b; prm.b2c = b2c;
    prm.gamma = gamma; prm.beta = beta; prm.fcw = fcw; prm.fcb = fcb;
    prm.WBhi = WBhi; prm.WBlo = WBlo; prm.T1hi = T1hi; prm.T1lo = T1lo;
    prm.parts = parts; prm.dpart = dpart; prm.out = out;

    void* args[] = { &prm };
    hipError_t err = hipLaunchCooperativeKernel((const void*)k_mega,
                                                dim3(NBLK), dim3(256), args, 0, stream);
    if (err != hipSuccess) {
        // fallback: proven 6-kernel chain
        k_wprep2<<<144, 256, 0, stream>>>(w2a, w2b, w2c, WBhi, WBlo);
        k_fused1<<<NCHUNK1, 256, 0, stream>>>(
            x, w1a, b1a, w1b, b1b, w1c, b1c, chw, chb, T1hi, T1lo);
        k_conv2m<<<dim3(NCHUNK2, NN), 256, 0, stream>>>(
            T1hi, T1lo, WBhi, WBlo, b2a, b2b, b2c, T2v, parts);
        k_statsfin<<<NN, 64, 0, stream>>>(parts, stats);
        k_dot<<<DOT_BLOCKS, 256, 0, stream>>>(T2v, stats, gamma, beta, fcw, dpart);
        k_final<<<1, 512, 0, stream>>>(dpart, fcb, out);
    }
}

// Round 6
// 33.538 us; speedup vs baseline: 4.9463x; 4.9463x over previous
//
#include <hip/hip_runtime.h>
#include <math.h>

#define NN 18
#define T_STEPS 1280
#define T1LEN 1278   // T-2 (after conv1)
#define T2LEN 1276   // T-4 (after conv2)
#define NPOS1 (T1LEN * NN)   // 23004
#define XTOT  (T_STEPS * NN) // 23040
#define PC1 32
#define NCHUNK1 ((NPOS1 + PC1 - 1) / PC1)  // 719
#define PREPBLK 144                         // 36864 / 256
#define TC2 64
#define NCHUNK2 ((T2LEN + TC2 - 1) / TC2)  // 20
#define NBLK (NCHUNK2 * NN)                // 360

typedef __attribute__((ext_vector_type(8))) short short8;
typedef __attribute__((ext_vector_type(4))) float f32x4;

__device__ __forceinline__ unsigned short f2bf(float v) {
    unsigned u = __builtin_bit_cast(unsigned, v);
    u = u + 0x7fff + ((u >> 16) & 1);          // RNE
    return (unsigned short)(u >> 16);
}
__device__ __forceinline__ float bf2f(unsigned short h) {
    unsigned u = ((unsigned)h) << 16;
    return __builtin_bit_cast(float, u);
}

// =========== K1: [b<719] normalize+conv1(GLU)+cheb(MFMA)+relu -> T1 hi/lo
//             [b>=719] conv2 weight hi/lo split, layout [kb][col][klocal] ===========
__global__ __launch_bounds__(256) void k_fused1x(const float* __restrict__ x,
        const float* __restrict__ w1a, const float* __restrict__ b1a,
        const float* __restrict__ w1b, const float* __restrict__ b1b,
        const float* __restrict__ w1c, const float* __restrict__ b1c,
        const float* __restrict__ cw, const float* __restrict__ cb,
        const float* __restrict__ w2a, const float* __restrict__ w2b,
        const float* __restrict__ w2c,
        unsigned short* __restrict__ T1hi, unsigned short* __restrict__ T1lo,
        unsigned short* __restrict__ WBhi, unsigned short* __restrict__ WBlo) {
    int b = blockIdx.x;
    int tid = threadIdx.x;
    if (b >= NCHUNK1) {
        // conv2 weight split (consumed by the NEXT kernels only)
        int i = (b - NCHUNK1) * 256 + tid;   // < 36864 exactly
        int klocal = i & 31;
        int col = (i >> 5) % 192;
        int kb = i / (192 * 32);
        int conv = col >> 6, co = col & 63;
        int k = kb >> 1, ci = (kb & 1) * 32 + klocal;
        const float* w = (conv == 0) ? w2a : (conv == 1 ? w2b : w2c);
        float v = w[co * 192 + ci * 3 + k];
        unsigned short hi = f2bf(v);
        WBhi[i] = hi;
        WBlo[i] = f2bf(v - bf2f(hi));
        return;
    }
    __shared__ float xs[72];
    __shared__ uint4 tileH4[256], tileL4[256];   // 32 pos x 64 bf16, XOR-swizzled
    unsigned short* tileH = (unsigned short*)tileH4;
    unsigned short* tileL = (unsigned short*)tileL4;
    int p0 = b * PC1;
    int np = min(PC1, NPOS1 - p0);
    for (int idx = tid; idx < PC1 + 36; idx += 256) {
        int g = p0 + idx;
        float v = (g < XTOT) ? x[g] : 0.f;
        xs[idx] = v / fmaxf(fabsf(v), 1e-12f);
    }
    __syncthreads();
    int l = tid & 63, w = tid >> 6;
    int c = l;   // conv1 output channel for this lane
    {
        float wa0 = w1a[c*3], wa1 = w1a[c*3+1], wa2 = w1a[c*3+2];
        float wb0 = w1b[c*3], wb1 = w1b[c*3+1], wb2 = w1b[c*3+2];
        float wc0 = w1c[c*3], wc1 = w1c[c*3+1], wc2 = w1c[c*3+2];
        float ba = b1a[c], bb = b1b[c], bc = b1c[c];
        #pragma unroll
        for (int j = 0; j < 8; ++j) {
            int pl = w * 8 + j;
            float x0 = xs[pl], x1 = xs[pl + 18], x2 = xs[pl + 36];
            float pa = fmaf(wa2, x2, fmaf(wa1, x1, fmaf(wa0, x0, ba)));
            float pb = fmaf(wb2, x2, fmaf(wb1, x1, fmaf(wb0, x0, bb)));
            float pc_ = fmaf(wc2, x2, fmaf(wc1, x1, fmaf(wc0, x0, bc)));
            float q = 1.0f / (1.0f + expf(-pb));
            float v = fmaxf(pa * q + pc_, 0.f);
            unsigned short hi = f2bf(v);
            int sw = pl * 64 + (((c >> 3) ^ (pl & 7)) << 3) + (c & 7);
            tileH[sw] = hi;
            tileL[sw] = f2bf(v - bf2f(hi));
        }
    }
    // cheb B fragments straight from cw (16KB table, L2-hot): wave w -> cols w*16..w*16+15
    int d = w * 16 + (l & 15);
    short8 cbh[2], cbl[2];
    #pragma unroll
    for (int kb = 0; kb < 2; ++kb) {
        #pragma unroll
        for (int j = 0; j < 8; ++j) {
            float v = cw[(kb * 32 + (l >> 4) * 8 + j) * 64 + d];
            unsigned short hi = f2bf(v);
            cbh[kb][j] = (short)hi;
            cbl[kb][j] = (short)f2bf(v - bf2f(hi));
        }
    }
    __syncthreads();
    f32x4 acc[2] = {{0.f,0.f,0.f,0.f},{0.f,0.f,0.f,0.f}};
    #pragma unroll
    for (int kb = 0; kb < 2; ++kb) {
        #pragma unroll
        for (int mt = 0; mt < 2; ++mt) {
            int row = mt * 16 + (l & 15);
            int cbi = kb * 4 + (l >> 4);
            int si = row * 8 + (cbi ^ (row & 7));
            short8 ah = __builtin_bit_cast(short8, tileH4[si]);
            short8 al = __builtin_bit_cast(short8, tileL4[si]);
            acc[mt] = __builtin_amdgcn_mfma_f32_16x16x32_bf16(ah, cbh[kb], acc[mt], 0, 0, 0);
            acc[mt] = __builtin_amdgcn_mfma_f32_16x16x32_bf16(al, cbh[kb], acc[mt], 0, 0, 0);
            acc[mt] = __builtin_amdgcn_mfma_f32_16x16x32_bf16(ah, cbl[kb], acc[mt], 0, 0, 0);
        }
    }
    float cbias = cb[d];
    #pragma unroll
    for (int mt = 0; mt < 2; ++mt) {
        #pragma unroll
        for (int r = 0; r < 4; ++r) {
            int p = mt * 16 + (l >> 4) * 4 + r;
            if (p < np) {
                float v = fmaxf(acc[mt][r] + cbias, 0.f);
                unsigned short hi = f2bf(v);
                int idx = (p0 + p) * 64 + d;
                T1hi[idx] = hi;
                T1lo[idx] = f2bf(v - bf2f(hi));
            }
        }
    }
}

// ---- shared device routine: conv2 MFMA -> h[16] (bit-identical in K2 and K3) ----
__device__ __forceinline__ void conv2_compute(
        const unsigned short* __restrict__ T1hi, const unsigned short* __restrict__ T1lo,
        const unsigned short* __restrict__ WBhi, const unsigned short* __restrict__ WBlo,
        const float* __restrict__ b2a, const float* __restrict__ b2b,
        const float* __restrict__ b2c,
        uint4* ldsH, uint4* ldsL,
        int node, int t0, int tid, float h[16], float* s_sum, float* s_sq) {
    int rows_valid = min(66, T1LEN - t0);
    const uint4* gh = (const uint4*)T1hi;
    const uint4* gl = (const uint4*)T1lo;
    for (int idx = tid; idx < 528; idx += 256) {
        int row = idx >> 3, cb2 = idx & 7;
        uint4 vh = {0,0,0,0}, vl = {0,0,0,0};
        if (row < rows_valid) {
            int g = ((t0 + row) * NN + node) * 8 + cb2;
            vh = gh[g]; vl = gl[g];
        }
        int s = row * 8 + (cb2 ^ (row & 7));
        ldsH[s] = vh; ldsL[s] = vl;
    }
    int l = tid & 63, w = tid >> 6;
    int co = w * 16 + (l & 15);
    __syncthreads();
    const uint4* wbh = (const uint4*)WBhi;
    const uint4* wbl = (const uint4*)WBlo;
    f32x4 acc[4][3];
    #pragma unroll
    for (int mt = 0; mt < 4; ++mt)
        #pragma unroll
        for (int ct = 0; ct < 3; ++ct)
            acc[mt][ct] = (f32x4){0.f, 0.f, 0.f, 0.f};
    for (int kb = 0; kb < 6; ++kb) {
        short8 bh[3], bl[3];
        #pragma unroll
        for (int ct = 0; ct < 3; ++ct) {
            int col = (w + 4 * ct) * 16 + (l & 15);
            int gi = (kb * 192 + col) * 4 + (l >> 4);
            bh[ct] = __builtin_bit_cast(short8, wbh[gi]);
            bl[ct] = __builtin_bit_cast(short8, wbl[gi]);
        }
        #pragma unroll
        for (int mt = 0; mt < 4; ++mt) {
            int row = mt * 16 + (l & 15) + (kb >> 1);
            int cb2 = (kb & 1) * 4 + (l >> 4);
            int si = row * 8 + (cb2 ^ (row & 7));
            short8 ah = __builtin_bit_cast(short8, ldsH[si]);
            short8 al = __builtin_bit_cast(short8, ldsL[si]);
            acc[mt][0] = __builtin_amdgcn_mfma_f32_16x16x32_bf16(ah, bh[0], acc[mt][0], 0, 0, 0);
            acc[mt][1] = __builtin_amdgcn_mfma_f32_16x16x32_bf16(ah, bh[1], acc[mt][1], 0, 0, 0);
            acc[mt][2] = __builtin_amdgcn_mfma_f32_16x16x32_bf16(ah, bh[2], acc[mt][2], 0, 0, 0);
            acc[mt][0] = __builtin_amdgcn_mfma_f32_16x16x32_bf16(al, bh[0], acc[mt][0], 0, 0, 0);
            acc[mt][1] = __builtin_amdgcn_mfma_f32_16x16x32_bf16(al, bh[1], acc[mt][1], 0, 0, 0);
            acc[mt][2] = __builtin_amdgcn_mfma_f32_16x16x32_bf16(al, bh[2], acc[mt][2], 0, 0, 0);
            acc[mt][0] = __builtin_amdgcn_mfma_f32_16x16x32_bf16(ah, bl[0], acc[mt][0], 0, 0, 0);
            acc[mt][1] = __builtin_amdgcn_mfma_f32_16x16x32_bf16(ah, bl[1], acc[mt][1], 0, 0, 0);
            acc[mt][2] = __builtin_amdgcn_mfma_f32_16x16x32_bf16(ah, bl[2], acc[mt][2], 0, 0, 0);
        }
    }
    float ba = b2a[co], bb = b2b[co], bc = b2c[co];
    float ssum = 0.f, ssq = 0.f;
    #pragma unroll
    for (int mt = 0; mt < 4; ++mt) {
        #pragma unroll
        for (int r = 0; r < 4; ++r) {
            int t = t0 + mt * 16 + (l >> 4) * 4 + r;
            float hv = 0.f;
            if (t < T2LEN) {
                float P = acc[mt][0][r] + ba, Q = acc[mt][1][r] + bb, Cc = acc[mt][2][r] + bc;
                float qs = 1.f / (1.f + expf(-Q));
                hv = fmaxf(fmaf(P, qs, Cc), 0.f);
                ssum += hv;
                ssq = fmaf(hv, hv, ssq);
            }
            h[mt * 4 + r] = hv;
        }
    }
    *s_sum = ssum; *s_sq = ssq;
}

// =========== K2: conv2 MFMA -> BN partials only (no T2 store) ===========
__global__ __launch_bounds__(256) void k_conv2s(
        const unsigned short* __restrict__ T1hi, const unsigned short* __restrict__ T1lo,
        const unsigned short* __restrict__ WBhi, const unsigned short* __restrict__ WBlo,
        const float* __restrict__ b2a, const float* __restrict__ b2b,
        const float* __restrict__ b2c, float* __restrict__ partials) {
    __shared__ uint4 ldsH[528], ldsL[528];
    __shared__ float rs[256], rq[256];
    int b = blockIdx.x;
    int node = b / NCHUNK2, chunk = b % NCHUNK2;
    int t0 = chunk * TC2;
    int tid = threadIdx.x;
    float h[16], s_sum, s_sq;
    conv2_compute(T1hi, T1lo, WBhi, WBlo, b2a, b2b, b2c, ldsH, ldsL,
                  node, t0, tid, h, &s_sum, &s_sq);
    rs[tid] = s_sum; rq[tid] = s_sq;
    __syncthreads();
    for (int off = 128; off > 0; off >>= 1) {
        if (tid < off) { rs[tid] += rs[tid + off]; rq[tid] += rq[tid + off]; }
        __syncthreads();
    }
    if (tid == 0) {
        partials[b * 2]     = rs[0];
        partials[b * 2 + 1] = rq[0];
    }
}

// =========== K3: recompute h (bit-identical) + stats finalize + BN + relu + dot ===========
__global__ __launch_bounds__(256) void k_dotbn(
        const unsigned short* __restrict__ T1hi, const unsigned short* __restrict__ T1lo,
        const unsigned short* __restrict__ WBhi, const unsigned short* __restrict__ WBlo,
        const float* __restrict__ b2a, const float* __restrict__ b2b,
        const float* __restrict__ b2c,
        const float* __restrict__ partials,
        const float* __restrict__ gamma, const float* __restrict__ beta,
        const float* __restrict__ fcw, float* __restrict__ dpart) {
    __shared__ uint4 ldsH[528], ldsL[528];
    __shared__ float rr[256];
    int b = blockIdx.x;
    int node = b / NCHUNK2, chunk = b % NCHUNK2;
    int t0 = chunk * TC2;
    int tid = threadIdx.x;
    float h[16], s_sum, s_sq;
    conv2_compute(T1hi, T1lo, WBhi, WBlo, b2a, b2b, b2c, ldsH, ldsL,
                  node, t0, tid, h, &s_sum, &s_sq);
    // stats finalize (redundant per thread, deterministic serial order)
    float s = 0.f, q = 0.f;
    #pragma unroll
    for (int i = 0; i < NCHUNK2; ++i) {
        s += partials[(node * NCHUNK2 + i) * 2];
        q += partials[(node * NCHUNK2 + i) * 2 + 1];
    }
    float cnt = (float)(T2LEN * 64);
    float mean = s / cnt;
    float var = q / cnt - mean * mean;
    float istd = rsqrtf(var + 1e-5f);
    float g = gamma[node], bt = beta[node];
    int l = tid & 63, w = tid >> 6;
    int co = w * 16 + (l & 15);
    float acc = 0.f;
    #pragma unroll
    for (int mt = 0; mt < 4; ++mt) {
        #pragma unroll
        for (int r = 0; r < 4; ++r) {
            int t = t0 + mt * 16 + (l >> 4) * 4 + r;
            if (t < T2LEN) {
                float v = fmaxf((h[mt * 4 + r] - mean) * istd * g + bt, 0.f);
                acc = fmaf(v, fcw[(t * NN + node) * 64 + co], acc);
            }
        }
    }
    rr[tid] = acc;
    __syncthreads();
    for (int off = 128; off > 0; off >>= 1) {
        if (tid < off) rr[tid] += rr[tid + off];
        __syncthreads();
    }
    if (tid == 0) dpart[b] = rr[0];
}

// =========== K4: final reduce + fc_b ===========
__global__ __launch_bounds__(256) void k_final(const float* __restrict__ dpart,
                                               const float* __restrict__ fcb,
                                               float* __restrict__ out) {
    __shared__ float r[256];
    float v = 0.f;
    for (int i = threadIdx.x; i < NBLK; i += 256) v += dpart[i];
    r[threadIdx.x] = v;
    __syncthreads();
    for (int off = 128; off > 0; off >>= 1) {
        if (threadIdx.x < off) r[threadIdx.x] += r[threadIdx.x + off];
        __syncthreads();
    }
    if (threadIdx.x == 0) out[0] = r[0] + fcb[0];
}

extern "C" void kernel_launch(void* const* d_in, const int* in_sizes, int n_in,
                              void* d_out, int out_size, void* d_ws, size_t ws_size,
                              hipStream_t stream) {
    const float* x     = (const float*)d_in[0];
    // d_in[1] edge_index, d_in[2] edge_weight: unused (ChebConv K=1 -> identity only)
    const float* w1a   = (const float*)d_in[3];
    const float* b1a   = (const float*)d_in[4];
    const float* w1b   = (const float*)d_in[5];
    const float* b1b   = (const float*)d_in[6];
    const float* w1c   = (const float*)d_in[7];
    const float* b1c   = (const float*)d_in[8];
    const float* chw   = (const float*)d_in[9];
    const float* chb   = (const float*)d_in[10];
    const float* w2a   = (const float*)d_in[11];
    const float* b2a   = (const float*)d_in[12];
    const float* w2b   = (const float*)d_in[13];
    const float* b2b   = (const float*)d_in[14];
    const float* w2c   = (const float*)d_in[15];
    const float* b2c   = (const float*)d_in[16];
    const float* gamma = (const float*)d_in[17];
    const float* beta  = (const float*)d_in[18];
    const float* fcw   = (const float*)d_in[19];
    const float* fcb   = (const float*)d_in[20];
    float* out = (float*)d_out;

    char* base = (char*)d_ws;
    unsigned short* T1hi  = (unsigned short*)(base);           // 2944512 B
    unsigned short* T1lo  = (unsigned short*)(base + 2944512); // 2944512 B
    unsigned short* WBhi  = (unsigned short*)(base + 5889024); // 73728 B
    unsigned short* WBlo  = (unsigned short*)(base + 5962752); // 73728 B
    float*          parts = (float*)(base + 6036480);          // 720 f
    float*          dpart = (float*)(base + 6039360);          // 360 f

    k_fused1x<<<NCHUNK1 + PREPBLK, 256, 0, stream>>>(
        x, w1a, b1a, w1b, b1b, w1c, b1c, chw, chb,
        w2a, w2b, w2c, T1hi, T1lo, WBhi, WBlo);
    k_conv2s<<<NBLK, 256, 0, stream>>>(
        T1hi, T1lo, WBhi, WBlo, b2a, b2b, b2c, parts);
    k_dotbn<<<NBLK, 256, 0, stream>>>(
        T1hi, T1lo, WBhi, WBlo, b2a, b2b, b2c, parts, gamma, beta, fcw, dpart);
    k_final<<<1, 256, 0, stream>>>(dpart, fcb, out);
}